// Round 6
// baseline (194.985 us; speedup 1.0000x reference)
//
#include <hip/hip_runtime.h>

// out[t][e] = (W[e][ids[t]] + b[e]) * sqrt(512)
// W: (512, 50257) row-major f32; ids: 32768 int32; out: 32768 x 512 f32.
//
// Round 10: max both DRAM granules simultaneously — the untried cell.
//  - VB=64: every staged W-row segment is 256 B, 256 B-aligned (4 full lines).
//  - Block = (bucket b, e-half z): stages 256 e-rows x 64 cols = 64 KB LDS,
//    ONE barrier, then scatter: one token per wave per iter, lane holds
//    e = z*256 + 4*lane + k -> ONE dwordx4 store = 1 KB contiguous.
//  - 512 threads/block, 1572 blocks, 2 blocks/CU (128 KB staged in flight/CU).
//  - Token list in REGISTERS (tok_a/tok_b) + readlane with WAVE-UNIFORM index
//    (i = w + 8*iter) -> no waterfall, no LDS toks, tile fits 64 KB exactly.
//  - LDS rotation swizzle via pre-rotated GLOBAL source (linear DMA dest,
//    guide rule 21): row r slot s holds col (s - r/4)&63; read slot
//    (vl + lane)&63 -> bank (vl+lane)%32, 2-way across 64 lanes = free.

constexpr int VOCAB = 50257;
constexpr int EMB   = 512;
constexpr int NTOK  = 8 * 4096;
constexpr float SCALE = 22.62741699796952f;  // sqrt(512)

constexpr int VB   = 64;                      // vocab ids per bucket
constexpr int NB   = (VOCAB + VB - 1) / VB;   // 786 buckets
constexpr int CAP  = 96;                      // capacity (mean 41.7, sigma 6.5)
constexpr int ECH  = 256;                     // e-rows per block (e-half)

// d_ws int layout: counts[NB] | ocount[1] | olist[NTOK] | buckets[NB*CAP]

__global__ __launch_bounds__(256) void build_buckets(
    const int* __restrict__ ids,
    int* __restrict__ counts,
    int* __restrict__ olist,
    int* __restrict__ buckets)
{
    int t = blockIdx.x * 256 + threadIdx.x;
    int id = ids[t];
    int bkt = id >> 6;
    int slot = atomicAdd(&counts[bkt], 1);
    if (slot < CAP) {
        buckets[bkt * CAP + slot] = (t << 6) | (id & 63);
    } else {
        int o = atomicAdd(&counts[NB], 1);
        olist[o] = t;
    }
}

__global__ __launch_bounds__(512) void scatter_main(
    const float* __restrict__ W,
    const float* __restrict__ bias,
    const int*   __restrict__ counts,
    const int*   __restrict__ buckets,
    const int*   __restrict__ olist,
    const int*   __restrict__ ids,
    float*       __restrict__ out)
{
    __shared__ float tile[ECH * VB];      // exactly 65,536 B

    const int bid  = blockIdx.x;
    const int b    = bid >> 1;            // bucket
    const int z    = bid & 1;             // e-half
    const int tid  = threadIdx.x;
    const int lane = tid & 63;
    const int w    = tid >> 6;            // wave id 0..7

    const int e0     = z * ECH;
    const int vstart = min(b * VB, VOCAB - VB);
    const int vadj   = b * VB - vstart;   // 0 except last bucket (47)

    // ---- scalar/register preloads (no LDS needed) ----
    const int cnt   = min(counts[b], CAP);             // uniform -> s_load
    const int tok_a = buckets[b * CAP + lane];         // slots 0..63
    const int tok_b = buckets[b * CAP + 64 + (lane & 31)]; // slots 64..95
    const float4 b4 = *reinterpret_cast<const float4*>(bias + e0 + 4 * lane);

    // ---- stage: 256 rows x 256 B, one row per width-4 DMA instruction ----
    // Wave w stages rows [w*32, w*32+32). Linear LDS dest; source column is
    // pre-rotated so slot s of row r holds col (s - (r>>2)) & 63.
    #pragma unroll
    for (int p = 0; p < 32; ++p) {
        const int r = w * 32 + p;
        const int srccol = (lane - (r >> 2)) & 63;
        const float* gp = W + (size_t)(e0 + r) * VOCAB + (vstart + srccol);
        float* lp = &tile[r * VB];
        __builtin_amdgcn_global_load_lds(
            (const __attribute__((address_space(1))) void*)gp,
            (__attribute__((address_space(3))) void*)lp, 4, 0, 0);
    }
    __syncthreads();                      // drains DMA; tile visible to all

    // ---- scatter: one token/wave/iter, ONE 1KB-contiguous dwordx4 store ----
    // Lane covers rows 4*lane+k (k=0..3); read slot = (vl + lane) & 63
    // for all k (since (4*lane+k)>>2 == lane): 2-way banked, free.
    for (int i = w; i < cnt; i += 8) {
        const int pk = (i < 64) ? __builtin_amdgcn_readlane(tok_a, i)
                                : __builtin_amdgcn_readlane(tok_b, i - 64);
        const int t  = pk >> 6;
        const int vl = (pk & 63) + vadj;
        const int s  = (vl + lane) & 63;
        float4 o;
        o.x = tile[(4 * lane + 0) * VB + s];
        o.y = tile[(4 * lane + 1) * VB + s];
        o.z = tile[(4 * lane + 2) * VB + s];
        o.w = tile[(4 * lane + 3) * VB + s];
        o.x = (o.x + b4.x) * SCALE;
        o.y = (o.y + b4.y) * SCALE;
        o.z = (o.z + b4.z) * SCALE;
        o.w = (o.w + b4.w) * SCALE;
        *reinterpret_cast<float4*>(out + (size_t)t * EMB + e0 + 4 * lane) = o;
    }

    // ---- overflow fix (expected n == 0): b==0 blocks, each its e-half ----
    if (b == 0) {
        int n = counts[NB];
        for (int ww = w; ww < n; ww += 8) {
            int t  = olist[ww];
            int id = ids[t];
            #pragma unroll
            for (int m = 0; m < 4; ++m) {
                int e = e0 + lane + m * 64;
                out[(size_t)t * EMB + e] = (W[(size_t)e * VOCAB + id] + bias[e]) * SCALE;
            }
        }
    }
}

// Fallback (round-1 kernel) if d_ws is too small.
__global__ __launch_bounds__(256) void embed_gather(
    const int*   __restrict__ ids,
    const float* __restrict__ W,
    const float* __restrict__ b,
    float*       __restrict__ out)
{
    int idx4 = blockIdx.x * blockDim.x + threadIdx.x;
    int t    = idx4 >> 7;
    int e    = (idx4 & 127) << 2;
    int id = ids[t];
    float4 bb = *reinterpret_cast<const float4*>(b + e);
    const float* wcol = W + (size_t)id;
    float4 o;
    o.x = (wcol[(size_t)(e + 0) * VOCAB] + bb.x) * SCALE;
    o.y = (wcol[(size_t)(e + 1) * VOCAB] + bb.y) * SCALE;
    o.z = (wcol[(size_t)(e + 2) * VOCAB] + bb.z) * SCALE;
    o.w = (wcol[(size_t)(e + 3) * VOCAB] + bb.w) * SCALE;
    *reinterpret_cast<float4*>(out + (size_t)idx4 * 4) = o;
}

extern "C" void kernel_launch(void* const* d_in, const int* in_sizes, int n_in,
                              void* d_out, int out_size, void* d_ws, size_t ws_size,
                              hipStream_t stream)
{
    const int*   ids  = (const int*)  d_in[0];
    const float* W    = (const float*)d_in[1];
    const float* bias = (const float*)d_in[2];
    float*       out  = (float*)d_out;

    const size_t ws_ints_needed = (size_t)NB + 1 + NTOK + (size_t)NB * CAP;

    if (ws_size >= ws_ints_needed * sizeof(int)) {
        int* counts  = (int*)d_ws;
        int* olist   = counts + NB + 1;
        int* buckets = olist + NTOK;

        hipMemsetAsync(counts, 0, (NB + 1) * sizeof(int), stream);
        build_buckets<<<NTOK / 256, 256, 0, stream>>>(ids, counts, olist, buckets);
        scatter_main<<<NB * 2, 512, 0, stream>>>(W, bias, counts, buckets,
                                                 olist, ids, out);
    } else {
        constexpr int total4 = NTOK * EMB / 4;
        embed_gather<<<total4 / 256, 256, 0, stream>>>(ids, W, bias, out);
    }
}